// Round 5
// baseline (901.490 us; speedup 1.0000x reference)
//
#include <hip/hip_runtime.h>
#include <math.h>

#define NN 50000
#define NE 800000
#define NF 512
#define NH 128
#define KF 4
#define NC 64
#define LRELU_ALPHA 0.2f
#define EPSF 1e-16f

// ---------------- workspace layout (float offsets) ----------------
#define OFF_H      0LL                                  // h (NN,512)
#define OFF_HP     (OFF_H + (long long)NN * NF)         // hp (NN,512)
#define OFF_REC    (OFF_HP + (long long)NN * NF)        // rec (NE int4) 16B aligned
#define OFF_XO0    (OFF_REC + 4LL * NE)                 // (NN,64)
#define OFF_EEO    (OFF_XO0 + (long long)NN * NC)       // (NE,)
#define OFF_SSRC   (OFF_EEO + (long long)NE)            // (NN,4)
#define OFF_SDST   (OFF_SSRC + (long long)NN * KF)
#define OFF_S1A    (OFF_SDST + (long long)NN * KF)
#define OFF_S2A    (OFF_S1A + (long long)NN * KF)
#define OFF_ROWSUM (OFF_S2A + (long long)NN * KF)       // (NN,4)
#define OFF_S1O    (OFF_ROWSUM + (long long)NN * KF)    // (NN,)
#define OFF_S2O    (OFF_S1O + NN)
#define OFF_START  (OFF_S2O + NN)                       // (NN+1) ints, pad to even+2
// ---- zeroed-each-call region starts here ----
#define OFF_CNT    (OFF_START + NN + 4)                 // NN ints
#define OFF_CURSOR (OFF_CNT + NN)                       // NN ints
#define OFF_ATT    (OFF_CURSOR + NN)                    // double (2 floats), 8B-aligned
#define WS_FLOATS  (OFF_ATT + 2)

// ---------------------------------------------------------------------------
// K1: h = x @ Wcat (f32), 128x128 tile, BK=16, 256 threads, 8x8 microtile.
// Register-prefetch pipeline: tile k+1 is loaded into VGPRs while tile k's
// FMA block runs, so global latency hides under compute. k-accumulation
// strictly sequential 0..511 per output -> h bitwise identical to previous
// rounds (top-2 factor selection cannot flip).
__global__ __launch_bounds__(256) void gemm_h(const float* __restrict__ x,
                                              const float* __restrict__ Wks,
                                              float* __restrict__ h) {
    __shared__ float As[16][128];   // transposed A tile: As[k][m]
    __shared__ float Bs[16][132];   // +4 pad spreads staging-write banks
    int m0 = blockIdx.y * 128;
    int n0 = blockIdx.x * 128;      // n0/128 = factor index
    const float* Bsrc = Wks + (size_t)(n0 >> 7) * (NF * NH);
    int tid = threadIdx.x;
    int tm = tid >> 4, tn = tid & 15;
    float acc[8][8];
#pragma unroll
    for (int i = 0; i < 8; ++i)
#pragma unroll
        for (int j = 0; j < 8; ++j) acc[i][j] = 0.f;

    int arow = tid >> 1;            // 0..127
    int akc  = (tid & 1) * 8;       // 0 or 8
    int am = m0 + arow; if (am >= NN) am = NN - 1;   // clamp; OOB rows not stored
    int brow = tid >> 4;            // 0..15
    int bcol = (tid & 15) * 8;      // 0..120

    const float* aptr = x + (size_t)am * NF + akc;
    const float* bptr = Bsrc + (size_t)brow * NH + bcol;

    float4 a0 = *(const float4*)(aptr);
    float4 a1 = *(const float4*)(aptr + 4);
    float4 b0 = *(const float4*)(bptr);
    float4 b1 = *(const float4*)(bptr + 4);

    for (int k0 = 0; k0 < NF; k0 += 16) {
        As[akc + 0][arow] = a0.x; As[akc + 1][arow] = a0.y;
        As[akc + 2][arow] = a0.z; As[akc + 3][arow] = a0.w;
        As[akc + 4][arow] = a1.x; As[akc + 5][arow] = a1.y;
        As[akc + 6][arow] = a1.z; As[akc + 7][arow] = a1.w;
        *(float4*)&Bs[brow][bcol]     = b0;
        *(float4*)&Bs[brow][bcol + 4] = b1;
        __syncthreads();
        if (k0 + 16 < NF) {   // prefetch next tile into regs; overlaps compute
            a0 = *(const float4*)(aptr + k0 + 16);
            a1 = *(const float4*)(aptr + k0 + 20);
            b0 = *(const float4*)(bptr + (size_t)(k0 + 16) * NH);
            b1 = *(const float4*)(bptr + (size_t)(k0 + 16) * NH + 4);
        }
#pragma unroll
        for (int kk = 0; kk < 16; ++kk) {
            float4 av0 = *(float4*)&As[kk][tm * 8];
            float4 av1 = *(float4*)&As[kk][tm * 8 + 4];
            float4 bv0 = *(float4*)&Bs[kk][tn * 4];
            float4 bv1 = *(float4*)&Bs[kk][64 + tn * 4];
            float a[8] = {av0.x, av0.y, av0.z, av0.w, av1.x, av1.y, av1.z, av1.w};
            float b[8] = {bv0.x, bv0.y, bv0.z, bv0.w, bv1.x, bv1.y, bv1.z, bv1.w};
#pragma unroll
            for (int i = 0; i < 8; ++i)
#pragma unroll
                for (int j = 0; j < 8; ++j)
                    acc[i][j] = fmaf(a[i], b[j], acc[i][j]);
        }
        __syncthreads();
    }
#pragma unroll
    for (int i = 0; i < 8; ++i) {
        int m = m0 + tm * 8 + i;
        if (m < NN) {
            float4 o0 = make_float4(acc[i][0], acc[i][1], acc[i][2], acc[i][3]);
            float4 o1 = make_float4(acc[i][4], acc[i][5], acc[i][6], acc[i][7]);
            *(float4*)(h + (size_t)m * NF + n0 + tn * 4)      = o0;
            *(float4*)(h + (size_t)m * NF + n0 + 64 + tn * 4) = o1;
        }
    }
}

// ---------------------------------------------------------------------------
// K2: routing/attention scalars from h (matches reference contraction h @ a).
__global__ __launch_bounds__(256) void compute_svals_h(
        const float* __restrict__ h, const float* __restrict__ a_k,
        const float* __restrict__ a_att,
        float* __restrict__ s_src, float* __restrict__ s_dst,
        float* __restrict__ s1a, float* __restrict__ s2a) {
    __shared__ float Ak[4][1024];
    __shared__ float Aa[4][256];
    for (int i = threadIdx.x; i < 4096; i += 256) Ak[i >> 10][i & 1023] = a_k[i];
    for (int i = threadIdx.x; i < 1024; i += 256) Aa[i >> 8][i & 255] = a_att[i];
    __syncthreads();
    int w = threadIdx.x >> 6, lane = threadIdx.x & 63;
    int n = blockIdx.x * 4 + w;
    if (n >= NN) return;
    const float* hr = h + (size_t)n * NF;
    float accS[4] = {0, 0, 0, 0}, accD[4] = {0, 0, 0, 0};
    float accQ1[4] = {0, 0, 0, 0}, accQ2[4] = {0, 0, 0, 0};
#pragma unroll
    for (int i = 0; i < 8; ++i) {
        int f = i * 64 + lane;
        float hv = hr[f];
#pragma unroll
        for (int k = 0; k < 4; ++k) {
            accS[k] = fmaf(hv, Ak[k][f], accS[k]);
            accD[k] = fmaf(hv, Ak[k][512 + f], accD[k]);
        }
        accQ1[i >> 1] = fmaf(hv, Aa[i >> 1][f & 127], accQ1[i >> 1]);
        accQ2[i >> 1] = fmaf(hv, Aa[i >> 1][128 + (f & 127)], accQ2[i >> 1]);
    }
#pragma unroll
    for (int off = 32; off >= 1; off >>= 1) {
#pragma unroll
        for (int k = 0; k < 4; ++k) {
            accS[k] += __shfl_xor(accS[k], off);
            accD[k] += __shfl_xor(accD[k], off);
            accQ1[k] += __shfl_xor(accQ1[k], off);
            accQ2[k] += __shfl_xor(accQ2[k], off);
        }
    }
    if (lane == 0) {
#pragma unroll
        for (int k = 0; k < 4; ++k) {
            s_src[n * 4 + k] = accS[k];
            s_dst[n * 4 + k] = accD[k];
            s1a[n * 4 + k]   = accQ1[k];
            s2a[n * 4 + k]   = accQ2[k];
        }
    }
}

// ---------------------------------------------------------------------------
// CSR build: count / scan
__global__ void csr_count(const int* __restrict__ edge, int* __restrict__ cnt) {
    int e = blockIdx.x * 256 + threadIdx.x;
    if (e < NE) atomicAdd(&cnt[edge[e]], 1);
}

__global__ __launch_bounds__(1024) void csr_scan(const int* __restrict__ cnt,
                                                 int* __restrict__ start) {
    __shared__ int part[1024];
    int t = threadIdx.x;
    const int CH = (NN + 1023) / 1024;  // 49
    int base = t * CH;
    int s = 0;
    for (int i = 0; i < CH; ++i) {
        int idx = base + i;
        if (idx < NN) s += cnt[idx];
    }
    part[t] = s;
    __syncthreads();
    for (int off = 1; off < 1024; off <<= 1) {
        int v = (t >= off) ? part[t - off] : 0;
        __syncthreads();
        part[t] += v;
        __syncthreads();
    }
    int run = (t == 0) ? 0 : part[t - 1];
    for (int i = 0; i < CH; ++i) {
        int idx = base + i;
        if (idx < NN) { start[idx] = run; run += cnt[idx]; }
    }
    if (t == 1023) start[NN] = run;
}

// ---------------------------------------------------------------------------
// K3: edge-parallel scalar precompute + CSR fill. One thread per edge.
__global__ __launch_bounds__(256) void edge_pre1(
        const int* __restrict__ edge, const int* __restrict__ start,
        int* __restrict__ cursor,
        const float* __restrict__ s_src, const float* __restrict__ s_dst,
        const float* __restrict__ s1a, const float* __restrict__ s2a,
        int4* __restrict__ rec, double* __restrict__ att_acc) {
    __shared__ float blk[4];
    int tid = threadIdx.x;
    int e = blockIdx.x * 256 + tid;
    float t2 = 0.f;
    if (e < NE) {
        int src = edge[e];
        int dst = edge[NE + e];
        float4 ss = *(const float4*)(s_src + (size_t)src * 4);
        float4 sd = *(const float4*)(s_dst + (size_t)dst * 4);
        float l0 = ss.x + sd.x, l1 = ss.y + sd.y, l2 = ss.z + sd.z, l3 = ss.w + sd.w;
        int i1 = 0; float v1 = l0;
        if (l1 > v1) { v1 = l1; i1 = 1; }
        if (l2 > v1) { v1 = l2; i1 = 2; }
        if (l3 > v1) { v1 = l3; i1 = 3; }
        int i2 = 0; float v2 = -3.4e38f;
        if (i1 != 0)            { v2 = l0; i2 = 0; }
        if (i1 != 1 && l1 > v2) { v2 = l1; i2 = 1; }
        if (i1 != 2 && l2 > v2) { v2 = l2; i2 = 2; }
        if (i1 != 3 && l3 > v2) { v2 = l3; i2 = 3; }
        float esum = expf(l0 - v1) + expf(l1 - v1) + expf(l2 - v1) + expf(l3 - v1);
        t2 = (1.f + expf(v2 - v1)) / esum;
        float4 q1 = *(const float4*)(s1a + (size_t)src * 4);
        float4 q2 = *(const float4*)(s2a + (size_t)dst * 4);
        float q1v1 = i1 == 0 ? q1.x : i1 == 1 ? q1.y : i1 == 2 ? q1.z : q1.w;
        float q2v1 = i1 == 0 ? q2.x : i1 == 1 ? q2.y : i1 == 2 ? q2.z : q2.w;
        float q1v2 = i2 == 0 ? q1.x : i2 == 1 ? q1.y : i2 == 2 ? q1.z : q1.w;
        float q2v2 = i2 == 0 ? q2.x : i2 == 1 ? q2.y : i2 == 2 ? q2.z : q2.w;
        float sv1 = q1v1 + q2v1, sv2 = q1v2 + q2v2;
        float ee1 = expf(-(sv1 >= 0.f ? sv1 : LRELU_ALPHA * sv1));
        float ee2 = expf(-(sv2 >= 0.f ? sv2 : LRELU_ALPHA * sv2));
        int p = start[src] + atomicAdd(&cursor[src], 1);
        rec[p] = make_int4(dst, src | (i1 << 16) | (i2 << 18),
                           __float_as_int(ee1), __float_as_int(ee2));
    }
#pragma unroll
    for (int off = 32; off >= 1; off >>= 1) t2 += __shfl_xor(t2, off);
    if ((tid & 63) == 0) blk[tid >> 6] = t2;
    __syncthreads();
    if (tid == 0)
        atomicAdd(att_acc, (double)(blk[0] + blk[1] + blk[2] + blk[3]));
}

// ---------------------------------------------------------------------------
// K4: layer-1 gather. One block per node; 4 waves SPLIT the record list
// (each record decoded once). Per record: 4 unconditional coalesced gathers
// (the two active factors' 128-float slices), accumulated into 8 static
// registers via wave-uniform switches. LDS cross-wave reduce at the end.
__global__ __launch_bounds__(256) void node_gather1(
        const int* __restrict__ start, const int4* __restrict__ rec,
        const float* __restrict__ h, float* __restrict__ hp,
        float* __restrict__ rowsum) {
    __shared__ float red[4][512];
    __shared__ float rsred[4][4];
    int n = blockIdx.x;
    int w = threadIdx.x >> 6, lane = threadIdx.x & 63;
    int j0 = start[n], j1 = start[n + 1];
    float a00 = 0.f, a01 = 0.f, a10 = 0.f, a11 = 0.f;
    float a20 = 0.f, a21 = 0.f, a30 = 0.f, a31 = 0.f;
    float rs0 = 0.f, rs1 = 0.f, rs2 = 0.f, rs3 = 0.f;
    for (int j = j0 + w; j < j1; j += 4) {
        int4 r = rec[j];
        int i1 = (r.y >> 16) & 3, i2 = (r.y >> 18) & 3;
        float w1 = __int_as_float(r.z), w2 = __int_as_float(r.w);
        const float* hr = h + (size_t)r.x * NF + lane;
        float v1a = hr[i1 * 128];          // 4 independent coalesced loads
        float v1b = hr[i1 * 128 + 64];
        float v2a = hr[i2 * 128];
        float v2b = hr[i2 * 128 + 64];
        switch (i1) {   // wave-uniform -> scalar branch, static acc regs
            case 0: a00 = fmaf(w1, v1a, a00); a01 = fmaf(w1, v1b, a01); rs0 += w1; break;
            case 1: a10 = fmaf(w1, v1a, a10); a11 = fmaf(w1, v1b, a11); rs1 += w1; break;
            case 2: a20 = fmaf(w1, v1a, a20); a21 = fmaf(w1, v1b, a21); rs2 += w1; break;
            default:a30 = fmaf(w1, v1a, a30); a31 = fmaf(w1, v1b, a31); rs3 += w1; break;
        }
        switch (i2) {
            case 0: a00 = fmaf(w2, v2a, a00); a01 = fmaf(w2, v2b, a01); rs0 += w2; break;
            case 1: a10 = fmaf(w2, v2a, a10); a11 = fmaf(w2, v2b, a11); rs1 += w2; break;
            case 2: a20 = fmaf(w2, v2a, a20); a21 = fmaf(w2, v2b, a21); rs2 += w2; break;
            default:a30 = fmaf(w2, v2a, a30); a31 = fmaf(w2, v2b, a31); rs3 += w2; break;
        }
    }
    red[w][lane]       = a00; red[w][64 + lane]  = a01;
    red[w][128 + lane] = a10; red[w][192 + lane] = a11;
    red[w][256 + lane] = a20; red[w][320 + lane] = a21;
    red[w][384 + lane] = a30; red[w][448 + lane] = a31;
    if (lane == 0) {
        rsred[w][0] = rs0; rsred[w][1] = rs1; rsred[w][2] = rs2; rsred[w][3] = rs3;
    }
    __syncthreads();
    int t = threadIdx.x;
    float s0 = (red[0][t] + red[1][t]) + (red[2][t] + red[3][t]);
    float s1 = (red[0][256 + t] + red[1][256 + t]) + (red[2][256 + t] + red[3][256 + t]);
    float* hpr = hp + (size_t)n * NF;
    hpr[t]       = s0;
    hpr[256 + t] = s1;
    if (t < 4)
        rowsum[n * 4 + t] = (rsred[0][t] + rsred[1][t]) + (rsred[2][t] + rsred[3][t]);
}

// ---------------------------------------------------------------------------
// K5: node pass as tiled GEMM. out_cat = elu(hp/(rowsum+eps)) fused into the
// A-staging; xo0 = out_cat @ W_o; s1o/s2o in the epilogue.
__global__ __launch_bounds__(256) void node_pass_gemm(
        const float* __restrict__ hp, const float* __restrict__ rowsum,
        const float* __restrict__ Wo, const float* __restrict__ a_out,
        float* __restrict__ xo0, float* __restrict__ s1o, float* __restrict__ s2o) {
    __shared__ float As[16][128];
    __shared__ float Bs[16][64];
    int m0 = blockIdx.x * 128;
    int tid = threadIdx.x;
    int tm = tid >> 4, tn = tid & 15;
    float acc[8][4];
#pragma unroll
    for (int i = 0; i < 8; ++i)
#pragma unroll
        for (int j = 0; j < 4; ++j) acc[i][j] = 0.f;

    int arow = tid >> 1;
    int akc  = (tid & 1) * 8;
    int am = m0 + arow; if (am >= NN) am = NN - 1;
    int brow = tid >> 4, bcol = (tid & 15) * 4;

    for (int k0 = 0; k0 < NF; k0 += 16) {
        float rs = rowsum[am * 4 + ((k0 + akc) >> 7)] + EPSF;
        float4 v0 = *(const float4*)(hp + (size_t)am * NF + k0 + akc);
        float4 v1 = *(const float4*)(hp + (size_t)am * NF + k0 + akc + 4);
        float v[8] = {v0.x, v0.y, v0.z, v0.w, v1.x, v1.y, v1.z, v1.w};
#pragma unroll
        for (int i = 0; i < 8; ++i) {
            float t = v[i] / rs;
            v[i] = t > 0.f ? t : expm1f(t);
        }
        As[akc + 0][arow] = v[0]; As[akc + 1][arow] = v[1];
        As[akc + 2][arow] = v[2]; As[akc + 3][arow] = v[3];
        As[akc + 4][arow] = v[4]; As[akc + 5][arow] = v[5];
        As[akc + 6][arow] = v[6]; As[akc + 7][arow] = v[7];
        *(float4*)&Bs[brow][bcol] =
            *(const float4*)(Wo + (size_t)(k0 + brow) * NC + bcol);
        __syncthreads();
#pragma unroll
        for (int kk = 0; kk < 16; ++kk) {
            float4 av0 = *(float4*)&As[kk][tm * 8];
            float4 av1 = *(float4*)&As[kk][tm * 8 + 4];
            float4 bv  = *(float4*)&Bs[kk][tn * 4];
            float a[8] = {av0.x, av0.y, av0.z, av0.w, av1.x, av1.y, av1.z, av1.w};
            float b[4] = {bv.x, bv.y, bv.z, bv.w};
#pragma unroll
            for (int i = 0; i < 8; ++i)
#pragma unroll
                for (int j = 0; j < 4; ++j)
                    acc[i][j] = fmaf(a[i], b[j], acc[i][j]);
        }
        __syncthreads();
    }
    float4 ao1 = *(const float4*)(a_out + tn * 4);
    float4 ao2 = *(const float4*)(a_out + 64 + tn * 4);
#pragma unroll
    for (int i = 0; i < 8; ++i) {
        int m = m0 + tm * 8 + i;
        float4 o = make_float4(acc[i][0], acc[i][1], acc[i][2], acc[i][3]);
        float p1 = o.x * ao1.x + o.y * ao1.y + o.z * ao1.z + o.w * ao1.w;
        float p2 = o.x * ao2.x + o.y * ao2.y + o.z * ao2.z + o.w * ao2.w;
#pragma unroll
        for (int off = 8; off >= 1; off >>= 1) {  // reduce across 16 tn lanes
            p1 += __shfl_xor(p1, off);
            p2 += __shfl_xor(p2, off);
        }
        if (m < NN) {
            *(float4*)(xo0 + (size_t)m * NC + tn * 4) = o;
            if (tn == 0) { s1o[m] = p1; s2o[m] = p2; }
        }
    }
}

// ---------------------------------------------------------------------------
// K6: layer-2 per-edge e-values at CSR positions (src recovered from rec).
__global__ __launch_bounds__(256) void edge_pre2(
        const int4* __restrict__ rec, const float* __restrict__ s1o,
        const float* __restrict__ s2o, float* __restrict__ eeo) {
    int p = blockIdx.x * 256 + threadIdx.x;
    if (p >= NE) return;
    int4 r = rec[p];
    int src = r.y & 0xFFFF;
    float sv = s1o[src] + s2o[r.x];
    eeo[p] = expf(-(sv >= 0.f ? sv : LRELU_ALPHA * sv));
}

// ---------------------------------------------------------------------------
// K7: output attention gather fused with elu + log-softmax. One block per
// node; 4 waves split the records, LDS reduce, softmax on wave 0.
__global__ __launch_bounds__(256) void node_gather2(
        const int* __restrict__ start, const int4* __restrict__ rec,
        const float* __restrict__ eeo, const float* __restrict__ xo0,
        float* __restrict__ out) {
    __shared__ float red[4][64];
    __shared__ float rsl[4];
    int n = blockIdx.x;
    int w = threadIdx.x >> 6, lane = threadIdx.x & 63;
    int j0 = start[n], j1 = start[n + 1];
    float acc = 0.f, rsum = 0.f;
    for (int j = j0 + w; j < j1; j += 4) {
        int d = rec[j].x;
        float e = eeo[j];
        acc = fmaf(e, xo0[(size_t)d * NC + lane], acc);
        rsum += e;
    }
    red[w][lane] = acc;
    if (lane == 0) rsl[w] = rsum;
    __syncthreads();
    if (w == 0) {
        float a = (red[0][lane] + red[1][lane]) + (red[2][lane] + red[3][lane]);
        float r = (rsl[0] + rsl[1]) + (rsl[2] + rsl[3]);
        float t = a / (r + EPSF);
        float v = t > 0.f ? t : expm1f(t);
        float m = v;
#pragma unroll
        for (int off = 32; off >= 1; off >>= 1) m = fmaxf(m, __shfl_xor(m, off));
        float p = expf(v - m);
#pragma unroll
        for (int off = 32; off >= 1; off >>= 1) p += __shfl_xor(p, off);
        out[(size_t)n * NC + lane] = v - m - logf(p);
    }
}

__global__ void finalize_att(const double* __restrict__ att_acc, float* __restrict__ out) {
    out[(size_t)NN * NC] = 1.f - (float)(att_acc[0] / (double)NE);
}

// ---------------------------------------------------------------------------
extern "C" void kernel_launch(void* const* d_in, const int* in_sizes, int n_in,
                              void* d_out, int out_size, void* d_ws, size_t ws_size,
                              hipStream_t stream) {
    const float* x     = (const float*)d_in[0];
    const int*   edge  = (const int*)d_in[1];
    const float* Wks   = (const float*)d_in[2];
    const float* a_k   = (const float*)d_in[3];
    const float* Wo    = (const float*)d_in[4];
    const float* a_att = (const float*)d_in[5];
    const float* a_out = (const float*)d_in[6];
    float* out = (float*)d_out;

    float* wsf = (float*)d_ws;
    float* h      = wsf + OFF_H;
    float* hp     = wsf + OFF_HP;
    int4*  rec    = (int4*)(wsf + OFF_REC);
    float* xo0    = wsf + OFF_XO0;
    float* eeo    = wsf + OFF_EEO;
    float* s_src  = wsf + OFF_SSRC;
    float* s_dst  = wsf + OFF_SDST;
    float* s1a    = wsf + OFF_S1A;
    float* s2a    = wsf + OFF_S2A;
    float* rowsum = wsf + OFF_ROWSUM;
    float* s1o    = wsf + OFF_S1O;
    float* s2o    = wsf + OFF_S2O;
    int*   startp = (int*)(wsf + OFF_START);
    int*   cnt    = (int*)(wsf + OFF_CNT);
    int*   cursor = (int*)(wsf + OFF_CURSOR);
    double* att   = (double*)(wsf + OFF_ATT);

    // zero only the accumulation region (cnt, cursor, att) every call
    size_t zero_bytes = (size_t)(WS_FLOATS - OFF_CNT) * sizeof(float);
    hipMemsetAsync((char*)d_ws + (size_t)OFF_CNT * sizeof(float), 0, zero_bytes, stream);

    gemm_h<<<dim3(4, (NN + 127) / 128), 256, 0, stream>>>(x, Wks, h);
    compute_svals_h<<<(NN + 3) / 4, 256, 0, stream>>>(h, a_k, a_att,
                                                      s_src, s_dst, s1a, s2a);
    csr_count<<<(NE + 255) / 256, 256, 0, stream>>>(edge, cnt);
    csr_scan<<<1, 1024, 0, stream>>>(cnt, startp);
    edge_pre1<<<(NE + 255) / 256, 256, 0, stream>>>(edge, startp, cursor,
                                                    s_src, s_dst, s1a, s2a, rec, att);
    node_gather1<<<NN, 256, 0, stream>>>(startp, rec, h, hp, rowsum);
    node_pass_gemm<<<(NN + 127) / 128, 256, 0, stream>>>(hp, rowsum, Wo, a_out,
                                                         xo0, s1o, s2o);
    edge_pre2<<<(NE + 255) / 256, 256, 0, stream>>>(rec, s1o, s2o, eeo);
    node_gather2<<<NN, 256, 0, stream>>>(startp, rec, eeo, xo0, out);
    finalize_att<<<1, 1, 0, stream>>>(att, out);
}

// Round 6
// 758.705 us; speedup vs baseline: 1.1882x; 1.1882x over previous
//
#include <hip/hip_runtime.h>
#include <math.h>

#define NN 50000
#define NE 800000
#define NF 512
#define NH 128
#define KF 4
#define NC 64
#define LRELU_ALPHA 0.2f
#define EPSF 1e-16f

typedef unsigned short u16;
typedef __attribute__((ext_vector_type(8))) short bf16x8;
typedef __attribute__((ext_vector_type(4))) float f32x4;

// ---------------- workspace layout (float offsets) ----------------
#define OFF_H      0LL                                  // h (NN,512)
#define OFF_HP     (OFF_H + (long long)NN * NF)         // hp (NN,512); ALSO xhi/xlo before node_gather1
#define OFF_REC    (OFF_HP + (long long)NN * NF)        // rec (NE int4); ALSO Wt split before edge_pre1
#define OFF_XO0    (OFF_REC + 4LL * NE)                 // (NN,64)
#define OFF_EEO    (OFF_XO0 + (long long)NN * NC)       // (NE,)
#define OFF_SSRC   (OFF_EEO + (long long)NE)            // (NN,4)
#define OFF_SDST   (OFF_SSRC + (long long)NN * KF)
#define OFF_S1A    (OFF_SDST + (long long)NN * KF)
#define OFF_S2A    (OFF_S1A + (long long)NN * KF)
#define OFF_ROWSUM (OFF_S2A + (long long)NN * KF)       // (NN,4)
#define OFF_S1O    (OFF_ROWSUM + (long long)NN * KF)    // (NN,)
#define OFF_S2O    (OFF_S1O + NN)
#define OFF_START  (OFF_S2O + NN)                       // (NN+1) ints, pad
// ---- zeroed-each-call region starts here ----
#define OFF_CNT    (OFF_START + NN + 4)                 // NN ints
#define OFF_CURSOR (OFF_CNT + NN)                       // NN ints
#define OFF_ATT    (OFF_CURSOR + NN)                    // double (2 floats)
#define WS_FLOATS  (OFF_ATT + 2)

__device__ __forceinline__ u16 bf16_rne(float f) {
    unsigned int u = __float_as_uint(f);
    return (u16)((u + 0x7FFFu + ((u >> 16) & 1u)) >> 16);
}
__device__ __forceinline__ float bf16_f(u16 b) {
    return __uint_as_float(((unsigned int)b) << 16);
}

// ---------------------------------------------------------------------------
// K0a: split x into hi/lo bf16 (RNE). 8 elements/thread.
__global__ __launch_bounds__(256) void split_x(const float* __restrict__ x,
                                               u16* __restrict__ xhi,
                                               u16* __restrict__ xlo) {
    size_t i = ((size_t)blockIdx.x * 256 + threadIdx.x) * 8;
    float4 v0 = *(const float4*)(x + i);
    float4 v1 = *(const float4*)(x + i + 4);
    float v[8] = {v0.x, v0.y, v0.z, v0.w, v1.x, v1.y, v1.z, v1.w};
    unsigned int hp[4], lp[4];
#pragma unroll
    for (int j = 0; j < 4; ++j) {
        u16 h0 = bf16_rne(v[2 * j]);
        u16 h1 = bf16_rne(v[2 * j + 1]);
        u16 l0 = bf16_rne(v[2 * j] - bf16_f(h0));
        u16 l1 = bf16_rne(v[2 * j + 1] - bf16_f(h1));
        hp[j] = (unsigned int)h0 | ((unsigned int)h1 << 16);
        lp[j] = (unsigned int)l0 | ((unsigned int)l1 << 16);
    }
    *(uint4*)(xhi + i) = make_uint4(hp[0], hp[1], hp[2], hp[3]);
    *(uint4*)(xlo + i) = make_uint4(lp[0], lp[1], lp[2], lp[3]);
}

// K0b: transpose + split W: Wt[kf*128+n][f] = split(Wks[kf][f][n]).
__global__ void split_w(const float* __restrict__ Wks,
                        u16* __restrict__ wthi, u16* __restrict__ wtlo) {
    int b = blockIdx.x;            // 0..511 = kf*128 + n
    int kf = b >> 7, n = b & 127;
    for (int f = threadIdx.x; f < NF; f += 256) {
        float v = Wks[(size_t)kf * (NF * NH) + (size_t)f * NH + n];
        u16 hb = bf16_rne(v);
        u16 lb = bf16_rne(v - bf16_f(hb));
        wthi[(size_t)b * NF + f] = hb;
        wtlo[(size_t)b * NF + f] = lb;
    }
}

// ---------------------------------------------------------------------------
// K1: h = x @ Wcat via 4-term split-bf16 MFMA (hi*hi + hi*lo + lo*hi + lo*lo
// into one f32 accumulator) ~= f32 GEMM accuracy. 128x128 tile, BK=32,
// 4 waves x 64x64 quadrant, mfma_f32_16x16x32_bf16.
// Verified C/D layout: col = lane&15, row = (lane>>4)*4 + reg.
#define LDST 40   // shorts per LDS row (32 data + 8 pad) = 80 B, 16B-aligned
__global__ __launch_bounds__(256) void gemm_h_mfma(
        const u16* __restrict__ xhi, const u16* __restrict__ xlo,
        const u16* __restrict__ wthi, const u16* __restrict__ wtlo,
        float* __restrict__ h) {
    __shared__ u16 Ah[128 * LDST], Al[128 * LDST];
    __shared__ u16 Bh[128 * LDST], Bl[128 * LDST];
    int m0 = blockIdx.y * 128, n0 = blockIdx.x * 128;
    int tid = threadIdx.x;
    int lane = tid & 63;
    int wave = tid >> 6, wm = wave >> 1, wn = wave & 1;
    f32x4 acc[4][4];
#pragma unroll
    for (int i = 0; i < 4; ++i)
#pragma unroll
        for (int j = 0; j < 4; ++j) acc[i][j] = (f32x4)(0.f);

    int srow = tid & 127;
    int isB = tid >> 7;
    int am = m0 + srow; if (am >= NN) am = NN - 1;   // clamp; OOB rows unused
    const u16* gh = isB ? (wthi + (size_t)(n0 + srow) * NF)
                        : (xhi + (size_t)am * NF);
    const u16* gl = isB ? (wtlo + (size_t)(n0 + srow) * NF)
                        : (xlo + (size_t)am * NF);
    u16* dh = (isB ? Bh : Ah) + srow * LDST;
    u16* dl = (isB ? Bl : Al) + srow * LDST;

    const int arow = wm * 64 + (lane & 15);
    const int brow = wn * 64 + (lane & 15);
    const int koff = (lane >> 4) * 8;

    for (int k0 = 0; k0 < NF; k0 += 32) {
        uint4 p0 = *(const uint4*)(gh + k0);
        uint4 p1 = *(const uint4*)(gh + k0 + 8);
        uint4 p2 = *(const uint4*)(gh + k0 + 16);
        uint4 p3 = *(const uint4*)(gh + k0 + 24);
        uint4 q0 = *(const uint4*)(gl + k0);
        uint4 q1 = *(const uint4*)(gl + k0 + 8);
        uint4 q2 = *(const uint4*)(gl + k0 + 16);
        uint4 q3 = *(const uint4*)(gl + k0 + 24);
        __syncthreads();   // previous step's frag reads complete
        *(uint4*)(dh)      = p0; *(uint4*)(dh + 8)  = p1;
        *(uint4*)(dh + 16) = p2; *(uint4*)(dh + 24) = p3;
        *(uint4*)(dl)      = q0; *(uint4*)(dl + 8)  = q1;
        *(uint4*)(dl + 16) = q2; *(uint4*)(dl + 24) = q3;
        __syncthreads();
        bf16x8 ah[4], al[4], bh[4], bl[4];
#pragma unroll
        for (int mi = 0; mi < 4; ++mi) {
            ah[mi] = *(const bf16x8*)(Ah + (arow + mi * 16) * LDST + koff);
            al[mi] = *(const bf16x8*)(Al + (arow + mi * 16) * LDST + koff);
        }
#pragma unroll
        for (int ni = 0; ni < 4; ++ni) {
            bh[ni] = *(const bf16x8*)(Bh + (brow + ni * 16) * LDST + koff);
            bl[ni] = *(const bf16x8*)(Bl + (brow + ni * 16) * LDST + koff);
        }
#pragma unroll
        for (int mi = 0; mi < 4; ++mi)
#pragma unroll
            for (int ni = 0; ni < 4; ++ni) {
                acc[mi][ni] = __builtin_amdgcn_mfma_f32_16x16x32_bf16(
                    ah[mi], bh[ni], acc[mi][ni], 0, 0, 0);
                acc[mi][ni] = __builtin_amdgcn_mfma_f32_16x16x32_bf16(
                    ah[mi], bl[ni], acc[mi][ni], 0, 0, 0);
                acc[mi][ni] = __builtin_amdgcn_mfma_f32_16x16x32_bf16(
                    al[mi], bh[ni], acc[mi][ni], 0, 0, 0);
                acc[mi][ni] = __builtin_amdgcn_mfma_f32_16x16x32_bf16(
                    al[mi], bl[ni], acc[mi][ni], 0, 0, 0);
            }
    }
#pragma unroll
    for (int mi = 0; mi < 4; ++mi) {
        int mbase = m0 + wm * 64 + mi * 16 + (lane >> 4) * 4;
#pragma unroll
        for (int ni = 0; ni < 4; ++ni) {
            int n = n0 + wn * 64 + ni * 16 + (lane & 15);
#pragma unroll
            for (int r = 0; r < 4; ++r) {
                int m = mbase + r;
                if (m < NN) h[(size_t)m * NF + n] = acc[mi][ni][r];
            }
        }
    }
}

// ---------------------------------------------------------------------------
// K2: routing/attention scalars from h (matches reference contraction h @ a).
__global__ __launch_bounds__(256) void compute_svals_h(
        const float* __restrict__ h, const float* __restrict__ a_k,
        const float* __restrict__ a_att,
        float* __restrict__ s_src, float* __restrict__ s_dst,
        float* __restrict__ s1a, float* __restrict__ s2a) {
    __shared__ float Ak[4][1024];
    __shared__ float Aa[4][256];
    for (int i = threadIdx.x; i < 4096; i += 256) Ak[i >> 10][i & 1023] = a_k[i];
    for (int i = threadIdx.x; i < 1024; i += 256) Aa[i >> 8][i & 255] = a_att[i];
    __syncthreads();
    int w = threadIdx.x >> 6, lane = threadIdx.x & 63;
    int n = blockIdx.x * 4 + w;
    if (n >= NN) return;
    const float* hr = h + (size_t)n * NF;
    float accS[4] = {0, 0, 0, 0}, accD[4] = {0, 0, 0, 0};
    float accQ1[4] = {0, 0, 0, 0}, accQ2[4] = {0, 0, 0, 0};
#pragma unroll
    for (int i = 0; i < 8; ++i) {
        int f = i * 64 + lane;
        float hv = hr[f];
#pragma unroll
        for (int k = 0; k < 4; ++k) {
            accS[k] = fmaf(hv, Ak[k][f], accS[k]);
            accD[k] = fmaf(hv, Ak[k][512 + f], accD[k]);
        }
        accQ1[i >> 1] = fmaf(hv, Aa[i >> 1][f & 127], accQ1[i >> 1]);
        accQ2[i >> 1] = fmaf(hv, Aa[i >> 1][128 + (f & 127)], accQ2[i >> 1]);
    }
#pragma unroll
    for (int off = 32; off >= 1; off >>= 1) {
#pragma unroll
        for (int k = 0; k < 4; ++k) {
            accS[k] += __shfl_xor(accS[k], off);
            accD[k] += __shfl_xor(accD[k], off);
            accQ1[k] += __shfl_xor(accQ1[k], off);
            accQ2[k] += __shfl_xor(accQ2[k], off);
        }
    }
    if (lane == 0) {
#pragma unroll
        for (int k = 0; k < 4; ++k) {
            s_src[n * 4 + k] = accS[k];
            s_dst[n * 4 + k] = accD[k];
            s1a[n * 4 + k]   = accQ1[k];
            s2a[n * 4 + k]   = accQ2[k];
        }
    }
}

// ---------------------------------------------------------------------------
// CSR build: count / scan
__global__ void csr_count(const int* __restrict__ edge, int* __restrict__ cnt) {
    int e = blockIdx.x * 256 + threadIdx.x;
    if (e < NE) atomicAdd(&cnt[edge[e]], 1);
}

__global__ __launch_bounds__(1024) void csr_scan(const int* __restrict__ cnt,
                                                 int* __restrict__ start) {
    __shared__ int part[1024];
    int t = threadIdx.x;
    const int CH = (NN + 1023) / 1024;  // 49
    int base = t * CH;
    int s = 0;
    for (int i = 0; i < CH; ++i) {
        int idx = base + i;
        if (idx < NN) s += cnt[idx];
    }
    part[t] = s;
    __syncthreads();
    for (int off = 1; off < 1024; off <<= 1) {
        int v = (t >= off) ? part[t - off] : 0;
        __syncthreads();
        part[t] += v;
        __syncthreads();
    }
    int run = (t == 0) ? 0 : part[t - 1];
    for (int i = 0; i < CH; ++i) {
        int idx = base + i;
        if (idx < NN) { start[idx] = run; run += cnt[idx]; }
    }
    if (t == 1023) start[NN] = run;
}

// ---------------------------------------------------------------------------
// K3: edge-parallel scalar precompute + CSR fill. One thread per edge.
__global__ __launch_bounds__(256) void edge_pre1(
        const int* __restrict__ edge, const int* __restrict__ start,
        int* __restrict__ cursor,
        const float* __restrict__ s_src, const float* __restrict__ s_dst,
        const float* __restrict__ s1a, const float* __restrict__ s2a,
        int4* __restrict__ rec, double* __restrict__ att_acc) {
    __shared__ float blk[4];
    int tid = threadIdx.x;
    int e = blockIdx.x * 256 + tid;
    float t2 = 0.f;
    if (e < NE) {
        int src = edge[e];
        int dst = edge[NE + e];
        float4 ss = *(const float4*)(s_src + (size_t)src * 4);
        float4 sd = *(const float4*)(s_dst + (size_t)dst * 4);
        float l0 = ss.x + sd.x, l1 = ss.y + sd.y, l2 = ss.z + sd.z, l3 = ss.w + sd.w;
        int i1 = 0; float v1 = l0;
        if (l1 > v1) { v1 = l1; i1 = 1; }
        if (l2 > v1) { v1 = l2; i1 = 2; }
        if (l3 > v1) { v1 = l3; i1 = 3; }
        int i2 = 0; float v2 = -3.4e38f;
        if (i1 != 0)            { v2 = l0; i2 = 0; }
        if (i1 != 1 && l1 > v2) { v2 = l1; i2 = 1; }
        if (i1 != 2 && l2 > v2) { v2 = l2; i2 = 2; }
        if (i1 != 3 && l3 > v2) { v2 = l3; i2 = 3; }
        float esum = expf(l0 - v1) + expf(l1 - v1) + expf(l2 - v1) + expf(l3 - v1);
        t2 = (1.f + expf(v2 - v1)) / esum;
        float4 q1 = *(const float4*)(s1a + (size_t)src * 4);
        float4 q2 = *(const float4*)(s2a + (size_t)dst * 4);
        float q1v1 = i1 == 0 ? q1.x : i1 == 1 ? q1.y : i1 == 2 ? q1.z : q1.w;
        float q2v1 = i1 == 0 ? q2.x : i1 == 1 ? q2.y : i1 == 2 ? q2.z : q2.w;
        float q1v2 = i2 == 0 ? q1.x : i2 == 1 ? q1.y : i2 == 2 ? q1.z : q1.w;
        float q2v2 = i2 == 0 ? q2.x : i2 == 1 ? q2.y : i2 == 2 ? q2.z : q2.w;
        float sv1 = q1v1 + q2v1, sv2 = q1v2 + q2v2;
        float ee1 = expf(-(sv1 >= 0.f ? sv1 : LRELU_ALPHA * sv1));
        float ee2 = expf(-(sv2 >= 0.f ? sv2 : LRELU_ALPHA * sv2));
        int p = start[src] + atomicAdd(&cursor[src], 1);
        rec[p] = make_int4(dst, src | (i1 << 16) | (i2 << 18),
                           __float_as_int(ee1), __float_as_int(ee2));
    }
#pragma unroll
    for (int off = 32; off >= 1; off >>= 1) t2 += __shfl_xor(t2, off);
    if ((tid & 63) == 0) blk[tid >> 6] = t2;
    __syncthreads();
    if (tid == 0)
        atomicAdd(att_acc, (double)(blk[0] + blk[1] + blk[2] + blk[3]));
}

// ---------------------------------------------------------------------------
// K4: layer-1 gather. One block per node; 4 waves split the record list.
__global__ __launch_bounds__(256) void node_gather1(
        const int* __restrict__ start, const int4* __restrict__ rec,
        const float* __restrict__ h, float* __restrict__ hp,
        float* __restrict__ rowsum) {
    __shared__ float red[4][512];
    __shared__ float rsred[4][4];
    int n = blockIdx.x;
    int w = threadIdx.x >> 6, lane = threadIdx.x & 63;
    int j0 = start[n], j1 = start[n + 1];
    float a00 = 0.f, a01 = 0.f, a10 = 0.f, a11 = 0.f;
    float a20 = 0.f, a21 = 0.f, a30 = 0.f, a31 = 0.f;
    float rs0 = 0.f, rs1 = 0.f, rs2 = 0.f, rs3 = 0.f;
    for (int j = j0 + w; j < j1; j += 4) {
        int4 r = rec[j];
        int i1 = (r.y >> 16) & 3, i2 = (r.y >> 18) & 3;
        float w1 = __int_as_float(r.z), w2 = __int_as_float(r.w);
        const float* hr = h + (size_t)r.x * NF + lane;
        float v1a = hr[i1 * 128];
        float v1b = hr[i1 * 128 + 64];
        float v2a = hr[i2 * 128];
        float v2b = hr[i2 * 128 + 64];
        switch (i1) {
            case 0: a00 = fmaf(w1, v1a, a00); a01 = fmaf(w1, v1b, a01); rs0 += w1; break;
            case 1: a10 = fmaf(w1, v1a, a10); a11 = fmaf(w1, v1b, a11); rs1 += w1; break;
            case 2: a20 = fmaf(w1, v1a, a20); a21 = fmaf(w1, v1b, a21); rs2 += w1; break;
            default:a30 = fmaf(w1, v1a, a30); a31 = fmaf(w1, v1b, a31); rs3 += w1; break;
        }
        switch (i2) {
            case 0: a00 = fmaf(w2, v2a, a00); a01 = fmaf(w2, v2b, a01); rs0 += w2; break;
            case 1: a10 = fmaf(w2, v2a, a10); a11 = fmaf(w2, v2b, a11); rs1 += w2; break;
            case 2: a20 = fmaf(w2, v2a, a20); a21 = fmaf(w2, v2b, a21); rs2 += w2; break;
            default:a30 = fmaf(w2, v2a, a30); a31 = fmaf(w2, v2b, a31); rs3 += w2; break;
        }
    }
    red[w][lane]       = a00; red[w][64 + lane]  = a01;
    red[w][128 + lane] = a10; red[w][192 + lane] = a11;
    red[w][256 + lane] = a20; red[w][320 + lane] = a21;
    red[w][384 + lane] = a30; red[w][448 + lane] = a31;
    if (lane == 0) {
        rsred[w][0] = rs0; rsred[w][1] = rs1; rsred[w][2] = rs2; rsred[w][3] = rs3;
    }
    __syncthreads();
    int t = threadIdx.x;
    float s0 = (red[0][t] + red[1][t]) + (red[2][t] + red[3][t]);
    float s1 = (red[0][256 + t] + red[1][256 + t]) + (red[2][256 + t] + red[3][256 + t]);
    float* hpr = hp + (size_t)n * NF;
    hpr[t]       = s0;
    hpr[256 + t] = s1;
    if (t < 4)
        rowsum[n * 4 + t] = (rsred[0][t] + rsred[1][t]) + (rsred[2][t] + rsred[3][t]);
}

// ---------------------------------------------------------------------------
// K5: node pass as tiled GEMM with fused elu + epilogue dots.
__global__ __launch_bounds__(256) void node_pass_gemm(
        const float* __restrict__ hp, const float* __restrict__ rowsum,
        const float* __restrict__ Wo, const float* __restrict__ a_out,
        float* __restrict__ xo0, float* __restrict__ s1o, float* __restrict__ s2o) {
    __shared__ float As[16][128];
    __shared__ float Bs[16][64];
    int m0 = blockIdx.x * 128;
    int tid = threadIdx.x;
    int tm = tid >> 4, tn = tid & 15;
    float acc[8][4];
#pragma unroll
    for (int i = 0; i < 8; ++i)
#pragma unroll
        for (int j = 0; j < 4; ++j) acc[i][j] = 0.f;

    int arow = tid >> 1;
    int akc  = (tid & 1) * 8;
    int am = m0 + arow; if (am >= NN) am = NN - 1;
    int brow = tid >> 4, bcol = (tid & 15) * 4;

    for (int k0 = 0; k0 < NF; k0 += 16) {
        float rs = rowsum[am * 4 + ((k0 + akc) >> 7)] + EPSF;
        float4 v0 = *(const float4*)(hp + (size_t)am * NF + k0 + akc);
        float4 v1 = *(const float4*)(hp + (size_t)am * NF + k0 + akc + 4);
        float v[8] = {v0.x, v0.y, v0.z, v0.w, v1.x, v1.y, v1.z, v1.w};
#pragma unroll
        for (int i = 0; i < 8; ++i) {
            float t = v[i] / rs;
            v[i] = t > 0.f ? t : expm1f(t);
        }
        As[akc + 0][arow] = v[0]; As[akc + 1][arow] = v[1];
        As[akc + 2][arow] = v[2]; As[akc + 3][arow] = v[3];
        As[akc + 4][arow] = v[4]; As[akc + 5][arow] = v[5];
        As[akc + 6][arow] = v[6]; As[akc + 7][arow] = v[7];
        *(float4*)&Bs[brow][bcol] =
            *(const float4*)(Wo + (size_t)(k0 + brow) * NC + bcol);
        __syncthreads();
#pragma unroll
        for (int kk = 0; kk < 16; ++kk) {
            float4 av0 = *(float4*)&As[kk][tm * 8];
            float4 av1 = *(float4*)&As[kk][tm * 8 + 4];
            float4 bv  = *(float4*)&Bs[kk][tn * 4];
            float a[8] = {av0.x, av0.y, av0.z, av0.w, av1.x, av1.y, av1.z, av1.w};
            float b[4] = {bv.x, bv.y, bv.z, bv.w};
#pragma unroll
            for (int i = 0; i < 8; ++i)
#pragma unroll
                for (int j = 0; j < 4; ++j)
                    acc[i][j] = fmaf(a[i], b[j], acc[i][j]);
        }
        __syncthreads();
    }
    float4 ao1 = *(const float4*)(a_out + tn * 4);
    float4 ao2 = *(const float4*)(a_out + 64 + tn * 4);
#pragma unroll
    for (int i = 0; i < 8; ++i) {
        int m = m0 + tm * 8 + i;
        float4 o = make_float4(acc[i][0], acc[i][1], acc[i][2], acc[i][3]);
        float p1 = o.x * ao1.x + o.y * ao1.y + o.z * ao1.z + o.w * ao1.w;
        float p2 = o.x * ao2.x + o.y * ao2.y + o.z * ao2.z + o.w * ao2.w;
#pragma unroll
        for (int off = 8; off >= 1; off >>= 1) {
            p1 += __shfl_xor(p1, off);
            p2 += __shfl_xor(p2, off);
        }
        if (m < NN) {
            *(float4*)(xo0 + (size_t)m * NC + tn * 4) = o;
            if (tn == 0) { s1o[m] = p1; s2o[m] = p2; }
        }
    }
}

// ---------------------------------------------------------------------------
// K6: layer-2 per-edge e-values at CSR positions.
__global__ __launch_bounds__(256) void edge_pre2(
        const int4* __restrict__ rec, const float* __restrict__ s1o,
        const float* __restrict__ s2o, float* __restrict__ eeo) {
    int p = blockIdx.x * 256 + threadIdx.x;
    if (p >= NE) return;
    int4 r = rec[p];
    int src = r.y & 0xFFFF;
    float sv = s1o[src] + s2o[r.x];
    eeo[p] = expf(-(sv >= 0.f ? sv : LRELU_ALPHA * sv));
}

// ---------------------------------------------------------------------------
// K7: output attention gather fused with elu + log-softmax.
__global__ __launch_bounds__(256) void node_gather2(
        const int* __restrict__ start, const int4* __restrict__ rec,
        const float* __restrict__ eeo, const float* __restrict__ xo0,
        float* __restrict__ out) {
    __shared__ float red[4][64];
    __shared__ float rsl[4];
    int n = blockIdx.x;
    int w = threadIdx.x >> 6, lane = threadIdx.x & 63;
    int j0 = start[n], j1 = start[n + 1];
    float acc = 0.f, rsum = 0.f;
    for (int j = j0 + w; j < j1; j += 4) {
        int d = rec[j].x;
        float e = eeo[j];
        acc = fmaf(e, xo0[(size_t)d * NC + lane], acc);
        rsum += e;
    }
    red[w][lane] = acc;
    if (lane == 0) rsl[w] = rsum;
    __syncthreads();
    if (w == 0) {
        float a = (red[0][lane] + red[1][lane]) + (red[2][lane] + red[3][lane]);
        float r = (rsl[0] + rsl[1]) + (rsl[2] + rsl[3]);
        float t = a / (r + EPSF);
        float v = t > 0.f ? t : expm1f(t);
        float m = v;
#pragma unroll
        for (int off = 32; off >= 1; off >>= 1) m = fmaxf(m, __shfl_xor(m, off));
        float p = expf(v - m);
#pragma unroll
        for (int off = 32; off >= 1; off >>= 1) p += __shfl_xor(p, off);
        out[(size_t)n * NC + lane] = v - m - logf(p);
    }
}

__global__ void finalize_att(const double* __restrict__ att_acc, float* __restrict__ out) {
    out[(size_t)NN * NC] = 1.f - (float)(att_acc[0] / (double)NE);
}

// ---------------------------------------------------------------------------
extern "C" void kernel_launch(void* const* d_in, const int* in_sizes, int n_in,
                              void* d_out, int out_size, void* d_ws, size_t ws_size,
                              hipStream_t stream) {
    const float* x     = (const float*)d_in[0];
    const int*   edge  = (const int*)d_in[1];
    const float* Wks   = (const float*)d_in[2];
    const float* a_k   = (const float*)d_in[3];
    const float* Wo    = (const float*)d_in[4];
    const float* a_att = (const float*)d_in[5];
    const float* a_out = (const float*)d_in[6];
    float* out = (float*)d_out;

    float* wsf = (float*)d_ws;
    float* h      = wsf + OFF_H;
    float* hp     = wsf + OFF_HP;
    int4*  rec    = (int4*)(wsf + OFF_REC);
    float* xo0    = wsf + OFF_XO0;
    float* eeo    = wsf + OFF_EEO;
    float* s_src  = wsf + OFF_SSRC;
    float* s_dst  = wsf + OFF_SDST;
    float* s1a    = wsf + OFF_S1A;
    float* s2a    = wsf + OFF_S2A;
    float* rowsum = wsf + OFF_ROWSUM;
    float* s1o    = wsf + OFF_S1O;
    float* s2o    = wsf + OFF_S2O;
    int*   startp = (int*)(wsf + OFF_START);
    int*   cnt    = (int*)(wsf + OFF_CNT);
    int*   cursor = (int*)(wsf + OFF_CURSOR);
    double* att   = (double*)(wsf + OFF_ATT);

    // Transient aliases (dead before their regions' real users run):
    // xhi/xlo live in the hp region (hp written only by node_gather1, later);
    // Wt_hi/lo live in the rec region (rec written only by edge_pre1, later).
    u16* xhi  = (u16*)(wsf + OFF_HP);
    u16* xlo  = xhi + (size_t)NN * NF;
    u16* wthi = (u16*)(wsf + OFF_REC);
    u16* wtlo = wthi + (size_t)KF * NH * NF;

    // zero only the accumulation region (cnt, cursor, att) every call
    size_t zero_bytes = (size_t)(WS_FLOATS - OFF_CNT) * sizeof(float);
    hipMemsetAsync((char*)d_ws + (size_t)OFF_CNT * sizeof(float), 0, zero_bytes, stream);

    split_x<<<(NN * NF / 8 + 255) / 256, 256, 0, stream>>>(x, xhi, xlo);
    split_w<<<KF * NH, 256, 0, stream>>>(Wks, wthi, wtlo);
    gemm_h_mfma<<<dim3(4, (NN + 127) / 128), 256, 0, stream>>>(xhi, xlo, wthi, wtlo, h);
    compute_svals_h<<<(NN + 3) / 4, 256, 0, stream>>>(h, a_k, a_att,
                                                      s_src, s_dst, s1a, s2a);
    csr_count<<<(NE + 255) / 256, 256, 0, stream>>>(edge, cnt);
    csr_scan<<<1, 1024, 0, stream>>>(cnt, startp);
    edge_pre1<<<(NE + 255) / 256, 256, 0, stream>>>(edge, startp, cursor,
                                                    s_src, s_dst, s1a, s2a, rec, att);
    node_gather1<<<NN, 256, 0, stream>>>(startp, rec, h, hp, rowsum);
    node_pass_gemm<<<(NN + 127) / 128, 256, 0, stream>>>(hp, rowsum, Wo, a_out,
                                                         xo0, s1o, s2o);
    edge_pre2<<<(NE + 255) / 256, 256, 0, stream>>>(rec, s1o, s2o, eeo);
    node_gather2<<<NN, 256, 0, stream>>>(startp, rec, eeo, xo0, out);
    finalize_att<<<1, 1, 0, stream>>>(att, out);
}